// Round 2
// baseline (6004.142 us; speedup 1.0000x reference)
//
#include <hip/hip_runtime.h>

#define IN_F 256
#define OUT_F 128
#define NUM_REL 4
#define BN 64      // nodes per bucket
#define PBX 64     // partition blocks per relation (must be 64: wave-scan width)
#define PT 512     // partition block threads

typedef unsigned int u32;
typedef unsigned short u16;
typedef unsigned char u8;

static __device__ __forceinline__ u16 f32_to_bf16(float f) {
    union { float f; u32 u; } c; c.f = f;
    u32 u = c.u;
    u32 r = (u + 0x7fffu + ((u >> 16) & 1u)) >> 16;   // RNE
    return (u16)r;
}
static __device__ __forceinline__ float bf16lo(u32 v) {
    union { u32 u; float f; } c; c.u = v << 16; return c.f;
}
static __device__ __forceinline__ float bf16hi(u32 v) {
    union { u32 u; float f; } c; c.u = v & 0xffff0000u; return c.f;
}

// ---------- P1: per-block LDS histograms over dst-buckets and src-buckets ----------
__global__ __launch_bounds__(PT) void p1_hist(const int* __restrict__ EI, u32* __restrict__ ghd,
                                              u32* __restrict__ ghs, int E, int NB, int r0) {
    int rr = blockIdx.y, x = blockIdx.x;
    int r = r0 + rr;
    const int* src = EI + (size_t)(2 * r) * E;
    const int* dst = src + E;
    extern __shared__ u32 sh[];           // hd[NB], hs[NB]
    u32* hd = sh; u32* hs = sh + NB;
    for (int i = threadIdx.x; i < 2 * NB; i += PT) sh[i] = 0;
    __syncthreads();
    int CH = (E + PBX - 1) / PBX;
    int lo = x * CH, hi = min(E, lo + CH);
    for (int e = lo + threadIdx.x; e < hi; e += PT) {
        atomicAdd(&hd[dst[e] >> 6], 1u);
        atomicAdd(&hs[src[e] >> 6], 1u);
    }
    __syncthreads();
    for (int b = threadIdx.x; b < NB; b += PT) {
        ghd[(size_t)(rr * NB + b) * PBX + x] = hd[b];
        ghs[(size_t)(rr * NB + b) * PBX + x] = hs[b];
    }
}

// ---------- P2a: per-bin exclusive scan over the PBX=64 block columns (one wave per bin) ----------
__global__ __launch_bounds__(256) void p2a_scan(u32* __restrict__ ghd, u32* __restrict__ ghs,
                                                u32* __restrict__ bintot, int BINS) {
    int wid = blockIdx.x * 4 + (threadIdx.x >> 6);
    int lane = threadIdx.x & 63;
    if (wid >= 2 * BINS) return;
    u32* g = (wid < BINS) ? ghd : ghs;
    int bin = (wid < BINS) ? wid : wid - BINS;
    u32 c = g[(size_t)bin * PBX + lane];
    u32 xv = c;
    #pragma unroll
    for (int s = 1; s < 64; s <<= 1) {
        u32 y = __shfl_up(xv, s);
        if (lane >= s) xv += y;
    }
    g[(size_t)bin * PBX + lane] = xv - c;       // exclusive within bin
    if (lane == 63) bintot[wid] = xv;           // bin total
}

// ---------- P2b: exclusive scan over bins (two segments: dst then src) ----------
__global__ __launch_bounds__(1024) void p2b_scan(const u32* __restrict__ bintot,
                                                 u32* __restrict__ binbase_d,
                                                 u32* __restrict__ binbase_s, int BINS) {
    __shared__ u32 s[1024];
    __shared__ u32 carry;
    int t = threadIdx.x;
    for (int seg = 0; seg < 2; seg++) {
        const u32* in = bintot + (size_t)seg * BINS;
        u32* out = seg ? binbase_s : binbase_d;
        if (t == 0) carry = 0;
        __syncthreads();
        for (int base = 0; base < BINS; base += 1024) {
            int i = base + t;
            u32 v = (i < BINS) ? in[i] : 0;
            s[t] = v;
            __syncthreads();
            for (int off = 1; off < 1024; off <<= 1) {
                u32 x = (t >= off) ? s[t - off] : 0;
                __syncthreads();
                s[t] += x;
                __syncthreads();
            }
            u32 incl = s[t]; u32 c0 = carry;
            if (i < BINS) out[i] = c0 + incl - v;
            __syncthreads();
            if (t == 1023) carry = c0 + incl;
            __syncthreads();
        }
        if (t == 0) out[BINS] = carry;
        __syncthreads();
    }
}

// ---------- P3: atomic-free (global) scatter into bucketed pools ----------
__global__ __launch_bounds__(PT) void p3_scatter(const int* __restrict__ EI,
                                                 const u32* __restrict__ ghd, const u32* __restrict__ ghs,
                                                 const u32* __restrict__ binbase_d, const u32* __restrict__ binbase_s,
                                                 u32* __restrict__ part_dst, u8* __restrict__ part_src,
                                                 int E, int NB, int r0) {
    int rr = blockIdx.y, x = blockIdx.x;
    int r = r0 + rr;
    const int* src = EI + (size_t)(2 * r) * E;
    const int* dst = src + E;
    extern __shared__ u32 sh[];           // base_d[NB] cur_d[NB] base_s[NB] cur_s[NB]
    u32* base_d = sh; u32* cur_d = sh + NB; u32* base_s = sh + 2 * NB; u32* cur_s = sh + 3 * NB;
    for (int b = threadIdx.x; b < NB; b += PT) {
        int bin = rr * NB + b;
        base_d[b] = binbase_d[bin] + ghd[(size_t)bin * PBX + x];
        base_s[b] = binbase_s[bin] + ghs[(size_t)bin * PBX + x];
        cur_d[b] = 0; cur_s[b] = 0;
    }
    __syncthreads();
    int CH = (E + PBX - 1) / PBX;
    int lo = x * CH, hi = min(E, lo + CH);
    for (int e = lo + threadIdx.x; e < hi; e += PT) {
        int sv = src[e], dv = dst[e];
        int db = dv >> 6, sb = sv >> 6;
        u32 rk = atomicAdd(&cur_d[db], 1u);
        part_dst[base_d[db] + rk] = ((u32)sv << 6) | (u32)(dv & 63);
        u32 rk2 = atomicAdd(&cur_s[sb], 1u);
        part_src[base_s[sb] + rk2] = (u8)(sv & 63);
    }
}

// ---------- out-degree count per src bucket -> out_norm ----------
__global__ __launch_bounds__(256) void srccount_kernel(const u8* __restrict__ part_src,
                                                       const u32* __restrict__ binbase_s,
                                                       float* __restrict__ out_norm, int N, int NB) {
    int b = blockIdx.x, rr = blockIdx.y;
    int bin = rr * NB + b;
    __shared__ u32 cnt[BN];
    int t = threadIdx.x;
    if (t < BN) cnt[t] = 0;
    __syncthreads();
    u32 lo = binbase_s[bin], hi = binbase_s[bin + 1];
    for (u32 i = lo + t; i < hi; i += 256) atomicAdd(&cnt[part_src[i]], 1u);
    __syncthreads();
    if (t < BN) {
        int node = b * BN + t;
        if (node < N) out_norm[(size_t)rr * N + node] = rsqrtf((float)max(cnt[t], 1u));
    }
}

// ---------- GEMM: h[rr] = (out_norm_rr * X) @ W[r0+rr], stored bf16 ----------
#define BM 64
#define BK 32
__global__ __launch_bounds__(256) void gemm_kernel(const float* __restrict__ X,
                                                   const float* __restrict__ W,
                                                   const float* __restrict__ out_normf,
                                                   u16* __restrict__ h, int N, int r0) {
    int rr = blockIdx.y;
    int r = r0 + rr;
    int row0 = blockIdx.x * BM;
    __shared__ float As[BK][BM + 1];
    __shared__ float Bs[BK][OUT_F];
    int t = threadIdx.x;
    int tx = t & 15, ty = t >> 4;
    float acc[4][8] = {};
    const float* Wr = W + (size_t)r * IN_F * OUT_F;
    const float* norm = out_normf + (size_t)rr * N;

    for (int k0 = 0; k0 < IN_F; k0 += BK) {
        #pragma unroll
        for (int l = 0; l < 2; l++) {
            int j = t + l * 256;
            int m = j >> 3, q = j & 7;
            int row = row0 + m;
            float4 v = make_float4(0.f, 0.f, 0.f, 0.f);
            float nv = 0.f;
            if (row < N) {
                v = *(const float4*)(X + (size_t)row * IN_F + k0 + q * 4);
                nv = norm[row];
            }
            As[q * 4 + 0][m] = v.x * nv;
            As[q * 4 + 1][m] = v.y * nv;
            As[q * 4 + 2][m] = v.z * nv;
            As[q * 4 + 3][m] = v.w * nv;
        }
        #pragma unroll
        for (int l = 0; l < 4; l++) {
            int j = t + l * 256;
            int k = j >> 5, q = j & 31;
            float4 v = *(const float4*)(Wr + (size_t)(k0 + k) * OUT_F + q * 4);
            *(float4*)&Bs[k][q * 4] = v;
        }
        __syncthreads();
        #pragma unroll
        for (int k = 0; k < BK; k++) {
            float a[4];
            #pragma unroll
            for (int i = 0; i < 4; i++) a[i] = As[k][ty * 4 + i];
            float4 b0 = *(float4*)&Bs[k][tx * 8];
            float4 b1 = *(float4*)&Bs[k][tx * 8 + 4];
            float bb[8] = {b0.x, b0.y, b0.z, b0.w, b1.x, b1.y, b1.z, b1.w};
            #pragma unroll
            for (int i = 0; i < 4; i++)
                #pragma unroll
                for (int jx = 0; jx < 8; jx++)
                    acc[i][jx] += a[i] * bb[jx];
        }
        __syncthreads();
    }
    u16* hr = h + (size_t)rr * N * OUT_F;
    #pragma unroll
    for (int i = 0; i < 4; i++) {
        int row = row0 + ty * 4 + i;
        if (row >= N) continue;
        u16 u[8];
        #pragma unroll
        for (int jx = 0; jx < 8; jx++) u[jx] = f32_to_bf16(acc[i][jx]);
        *(uint4*)(hr + (size_t)row * OUT_F + tx * 8) = *(uint4*)u;
    }
}

// ---------- bucket-LDS aggregate: acc over edges, fuse in_norm, write Z ----------
__global__ __launch_bounds__(256) void aggregate_kernel(const u32* __restrict__ part_dst,
                                                        const u32* __restrict__ binbase_d,
                                                        const u16* __restrict__ h,
                                                        float* __restrict__ Z,
                                                        int N, int NB, int nrel, int accflag) {
    int b = blockIdx.x;
    __shared__ float acc[BN * OUT_F];     // 32 KB; word w = (feat&1)*64 + feat/2  (bank-conflict-free ds_add)
    __shared__ u32 cnt[BN];
    int t = threadIdx.x;
    int wv = t >> 6, lane = t & 63;
    float zacc[32];
    #pragma unroll
    for (int k = 0; k < 32; k++) zacc[k] = 0.f;
    for (int i = t; i < BN * OUT_F; i += 256) acc[i] = 0.f;
    if (t < BN) cnt[t] = 0;
    __syncthreads();

    for (int rr = 0; rr < nrel; rr++) {
        int bin = rr * NB + b;
        u32 lo = binbase_d[bin], hi = binbase_d[bin + 1];
        const u32* hr = (const u32*)(h + (size_t)rr * N * OUT_F);   // 64 dwords per row
        for (u32 i0 = lo + (u32)wv * 64u; i0 < hi; i0 += 256u) {
            int m = (int)min(64u, hi - i0);
            u32 v = (lane < m) ? part_dst[i0 + lane] : 0;
            for (int j0 = 0; j0 < m; j0 += 8) {
                u32 pe[8], ph[8];
                #pragma unroll
                for (int q = 0; q < 8; q++) {
                    int j = j0 + q;
                    if (j < m) {
                        pe[q] = __shfl(v, j);
                        ph[q] = hr[(size_t)(pe[q] >> 6) * (OUT_F / 2) + lane];
                    }
                }
                #pragma unroll
                for (int q = 0; q < 8; q++) {
                    int j = j0 + q;
                    if (j < m) {
                        int dl = (int)(pe[q] & 63u);
                        atomicAdd(&acc[dl * OUT_F + lane], bf16lo(ph[q]));
                        atomicAdd(&acc[dl * OUT_F + 64 + lane], bf16hi(ph[q]));
                        if (lane == 0) atomicAdd(&cnt[dl], 1u);
                    }
                }
            }
        }
        __syncthreads();
        #pragma unroll
        for (int k = 0; k < 32; k++) {
            int u = k * 256 + t;
            int node = u >> 7, feat = u & 127;
            int w = (feat & 1) * 64 + (feat >> 1);
            float inr = rsqrtf((float)max(cnt[node], 1u));
            zacc[k] += inr * acc[node * OUT_F + w];
        }
        __syncthreads();
        for (int i = t; i < BN * OUT_F; i += 256) acc[i] = 0.f;
        if (t < BN) cnt[t] = 0;
        __syncthreads();
    }

    int gbase = b * BN;
    #pragma unroll
    for (int k = 0; k < 32; k++) {
        int u = k * 256 + t;
        int node = u >> 7, feat = u & 127;
        int g = gbase + node;
        if (g < N) {
            float* zp = &Z[(size_t)g * OUT_F + feat];
            if (accflag) *zp += zacc[k]; else *zp = zacc[k];
        }
    }
}

// ---------- host ----------
extern "C" void kernel_launch(void* const* d_in, const int* in_sizes, int n_in,
                              void* d_out, int out_size, void* d_ws, size_t ws_size,
                              hipStream_t stream) {
    const float* X = (const float*)d_in[0];
    const float* W = (const float*)d_in[1];
    const int* EI = (const int*)d_in[2];
    float* Z = (float*)d_out;
    const int N = in_sizes[0] / IN_F;
    const int E = in_sizes[2] / (NUM_REL * 2);
    const int NB = (N + BN - 1) / BN;

    // workspace layout (sized per batch of nb relations); ghd/ghs/bintot/part_src overlay the h region
    size_t part_dst_o, out_norm_o, bbd_o, bbs_o, h_o, ghd_o, ghs_o, bintot_o, part_src_o;
    auto layout = [&](int nb) -> size_t {
        size_t off = 0;
        auto alloc = [&](size_t bytes) {
            size_t o = off; off = (off + bytes + 255) & ~(size_t)255; return o;
        };
        int BINS = nb * NB;
        size_t TE = (size_t)nb * E;
        part_dst_o = alloc(TE * 4);
        out_norm_o = alloc((size_t)nb * N * 4);
        bbd_o      = alloc((size_t)(BINS + 1) * 4);
        bbs_o      = alloc((size_t)(BINS + 1) * 4);
        h_o        = alloc((size_t)nb * N * OUT_F * 2);
        // overlay (inside h region; all consumed before gemm writes h)
        size_t ov = h_o;
        auto oalloc = [&](size_t bytes) {
            size_t o = ov; ov = (ov + bytes + 255) & ~(size_t)255; return o;
        };
        ghd_o      = oalloc((size_t)BINS * PBX * 4);
        ghs_o      = oalloc((size_t)BINS * PBX * 4);
        bintot_o   = oalloc((size_t)2 * BINS * 4);
        part_src_o = oalloc(TE);
        return (ov > off) ? ov : off;
    };
    int nb = NUM_REL;
    while (nb > 1 && layout(nb) > ws_size) nb >>= 1;
    layout(nb);
    char* ws = (char*)d_ws;
    const int nbatches = (NUM_REL + nb - 1) / nb;

    if (nbatches > 1)
        hipMemsetAsync(d_out, 0, (size_t)N * OUT_F * sizeof(float), stream);

    for (int r0 = 0; r0 < NUM_REL; r0 += nb) {
        int cur = min(nb, NUM_REL - r0);
        int BINS = cur * NB;
        u32* part_dst = (u32*)(ws + part_dst_o);
        float* out_norm = (float*)(ws + out_norm_o);
        u32* bbd = (u32*)(ws + bbd_o);
        u32* bbs = (u32*)(ws + bbs_o);
        u16* h = (u16*)(ws + h_o);
        u32* ghd = (u32*)(ws + ghd_o);
        u32* ghs = (u32*)(ws + ghs_o);
        u32* bintot = (u32*)(ws + bintot_o);
        u8* part_src = (u8*)(ws + part_src_o);

        p1_hist<<<dim3(PBX, cur), PT, 2 * NB * 4, stream>>>(EI, ghd, ghs, E, NB, r0);
        p2a_scan<<<(2 * BINS + 3) / 4, 256, 0, stream>>>(ghd, ghs, bintot, BINS);
        p2b_scan<<<1, 1024, 0, stream>>>(bintot, bbd, bbs, BINS);
        p3_scatter<<<dim3(PBX, cur), PT, 4 * NB * 4, stream>>>(
            EI, ghd, ghs, bbd, bbs, part_dst, part_src, E, NB, r0);
        srccount_kernel<<<dim3(NB, cur), 256, 0, stream>>>(part_src, bbs, out_norm, N, NB);
        gemm_kernel<<<dim3((N + BM - 1) / BM, cur), 256, 0, stream>>>(X, W, out_norm, h, N, r0);
        aggregate_kernel<<<NB, 256, 0, stream>>>(part_dst, bbd, h, Z, N, NB, cur,
                                                 (nbatches > 1) ? 1 : 0);
    }
}

// Round 3
// 597.557 us; speedup vs baseline: 10.0478x; 10.0478x over previous
//
#include <hip/hip_runtime.h>

#define IN_F 256
#define OUT_F 128
#define NUM_REL 4
#define BN 64      // nodes per bucket
#define PBX 64     // partition blocks per relation (must be 64: wave-scan width)
#define PT 512     // partition block threads

typedef unsigned int u32;
typedef unsigned short u16;
typedef unsigned char u8;

static __device__ __forceinline__ u16 f32_to_bf16(float f) {
    union { float f; u32 u; } c; c.f = f;
    u32 u = c.u;
    u32 r = (u + 0x7fffu + ((u >> 16) & 1u)) >> 16;   // RNE
    return (u16)r;
}
static __device__ __forceinline__ float bf16lo(u32 v) {
    union { u32 u; float f; } c; c.u = v << 16; return c.f;
}
static __device__ __forceinline__ float bf16hi(u32 v) {
    union { u32 u; float f; } c; c.u = v & 0xffff0000u; return c.f;
}

// ---------- P1: per-block LDS histograms over dst-buckets and src-buckets ----------
__global__ __launch_bounds__(PT) void p1_hist(const int* __restrict__ EI, u32* __restrict__ ghd,
                                              u32* __restrict__ ghs, int E, int NB, int r0) {
    int rr = blockIdx.y, x = blockIdx.x;
    int r = r0 + rr;
    const int* src = EI + (size_t)(2 * r) * E;
    const int* dst = src + E;
    extern __shared__ u32 sh[];           // hd[NB], hs[NB]
    u32* hd = sh; u32* hs = sh + NB;
    for (int i = threadIdx.x; i < 2 * NB; i += PT) sh[i] = 0;
    __syncthreads();
    int CH = (E + PBX - 1) / PBX;
    int lo = x * CH, hi = min(E, lo + CH);
    for (int e = lo + threadIdx.x; e < hi; e += PT) {
        atomicAdd(&hd[dst[e] >> 6], 1u);
        atomicAdd(&hs[src[e] >> 6], 1u);
    }
    __syncthreads();
    for (int b = threadIdx.x; b < NB; b += PT) {
        ghd[(size_t)(rr * NB + b) * PBX + x] = hd[b];
        ghs[(size_t)(rr * NB + b) * PBX + x] = hs[b];
    }
}

// ---------- P2a: per-bin exclusive scan over the PBX=64 block columns (one wave per bin) ----------
__global__ __launch_bounds__(256) void p2a_scan(u32* __restrict__ ghd, u32* __restrict__ ghs,
                                                u32* __restrict__ bintot, int BINS) {
    int wid = blockIdx.x * 4 + (threadIdx.x >> 6);
    int lane = threadIdx.x & 63;
    if (wid >= 2 * BINS) return;
    u32* g = (wid < BINS) ? ghd : ghs;
    int bin = (wid < BINS) ? wid : wid - BINS;
    u32 c = g[(size_t)bin * PBX + lane];
    u32 xv = c;
    #pragma unroll
    for (int s = 1; s < 64; s <<= 1) {
        u32 y = __shfl_up(xv, s);
        if (lane >= s) xv += y;
    }
    g[(size_t)bin * PBX + lane] = xv - c;       // exclusive within bin
    if (lane == 63) bintot[wid] = xv;           // bin total
}

// ---------- P2b: exclusive scan over bins (two segments: dst then src) ----------
__global__ __launch_bounds__(1024) void p2b_scan(const u32* __restrict__ bintot,
                                                 u32* __restrict__ binbase_d,
                                                 u32* __restrict__ binbase_s, int BINS) {
    __shared__ u32 s[1024];
    __shared__ u32 carry;
    int t = threadIdx.x;
    for (int seg = 0; seg < 2; seg++) {
        const u32* in = bintot + (size_t)seg * BINS;
        u32* out = seg ? binbase_s : binbase_d;
        if (t == 0) carry = 0;
        __syncthreads();
        for (int base = 0; base < BINS; base += 1024) {
            int i = base + t;
            u32 v = (i < BINS) ? in[i] : 0;
            s[t] = v;
            __syncthreads();
            for (int off = 1; off < 1024; off <<= 1) {
                u32 x = (t >= off) ? s[t - off] : 0;
                __syncthreads();
                s[t] += x;
                __syncthreads();
            }
            u32 incl = s[t]; u32 c0 = carry;
            if (i < BINS) out[i] = c0 + incl - v;
            __syncthreads();
            if (t == 1023) carry = c0 + incl;
            __syncthreads();
        }
        if (t == 0) out[BINS] = carry;
        __syncthreads();
    }
}

// ---------- P3: atomic-free (global) scatter into bucketed pools ----------
__global__ __launch_bounds__(PT) void p3_scatter(const int* __restrict__ EI,
                                                 const u32* __restrict__ ghd, const u32* __restrict__ ghs,
                                                 const u32* __restrict__ binbase_d, const u32* __restrict__ binbase_s,
                                                 u32* __restrict__ part_dst, u8* __restrict__ part_src,
                                                 int E, int NB, int r0) {
    int rr = blockIdx.y, x = blockIdx.x;
    int r = r0 + rr;
    const int* src = EI + (size_t)(2 * r) * E;
    const int* dst = src + E;
    extern __shared__ u32 sh[];           // base_d[NB] cur_d[NB] base_s[NB] cur_s[NB]
    u32* base_d = sh; u32* cur_d = sh + NB; u32* base_s = sh + 2 * NB; u32* cur_s = sh + 3 * NB;
    for (int b = threadIdx.x; b < NB; b += PT) {
        int bin = rr * NB + b;
        base_d[b] = binbase_d[bin] + ghd[(size_t)bin * PBX + x];
        base_s[b] = binbase_s[bin] + ghs[(size_t)bin * PBX + x];
        cur_d[b] = 0; cur_s[b] = 0;
    }
    __syncthreads();
    int CH = (E + PBX - 1) / PBX;
    int lo = x * CH, hi = min(E, lo + CH);
    for (int e = lo + threadIdx.x; e < hi; e += PT) {
        int sv = src[e], dv = dst[e];
        int db = dv >> 6, sb = sv >> 6;
        u32 rk = atomicAdd(&cur_d[db], 1u);
        part_dst[base_d[db] + rk] = ((u32)sv << 6) | (u32)(dv & 63);
        u32 rk2 = atomicAdd(&cur_s[sb], 1u);
        part_src[base_s[sb] + rk2] = (u8)(sv & 63);
    }
}

// ---------- out-degree count per src bucket -> out_norm ----------
__global__ __launch_bounds__(256) void srccount_kernel(const u8* __restrict__ part_src,
                                                       const u32* __restrict__ binbase_s,
                                                       float* __restrict__ out_norm, int N, int NB) {
    int b = blockIdx.x, rr = blockIdx.y;
    int bin = rr * NB + b;
    __shared__ u32 cnt[BN];
    int t = threadIdx.x;
    if (t < BN) cnt[t] = 0;
    __syncthreads();
    u32 lo = binbase_s[bin], hi = binbase_s[bin + 1];
    for (u32 i = lo + t; i < hi; i += 256) atomicAdd(&cnt[part_src[i]], 1u);
    __syncthreads();
    if (t < BN) {
        int node = b * BN + t;
        if (node < N) out_norm[(size_t)rr * N + node] = rsqrtf((float)max(cnt[t], 1u));
    }
}

// ---------- P4: within-bucket counting sort -> full per-node CSR (offsets + u16 src list) ----------
__global__ __launch_bounds__(256) void p4_sort(const u32* __restrict__ part_dst,
                                               const u32* __restrict__ binbase_d,
                                               u32* __restrict__ offs, u16* __restrict__ sorted,
                                               int N, int NB, int nrel) {
    int b = blockIdx.x, rr = blockIdx.y;
    int bin = rr * NB + b;
    __shared__ u32 cnt[BN];
    int t = threadIdx.x;
    if (t < BN) cnt[t] = 0;
    __syncthreads();
    u32 lo = binbase_d[bin], hi = binbase_d[bin + 1];
    for (u32 i = lo + t; i < hi; i += 256) atomicAdd(&cnt[part_dst[i] & 63u], 1u);
    __syncthreads();
    if (t < BN) {
        u32 c = cnt[t];
        u32 x = c;
        #pragma unroll
        for (int s = 1; s < 64; s <<= 1) {
            u32 y = __shfl_up(x, s);
            if (t >= s) x += y;
        }
        u32 excl = x - c;
        int node = b * BN + t;
        if (node < N) offs[(size_t)rr * N + node] = lo + excl;
        cnt[t] = excl;                    // becomes the scatter cursor
    }
    __syncthreads();
    for (u32 i = lo + t; i < hi; i += 256) {
        u32 p = part_dst[i];
        u32 pos = atomicAdd(&cnt[p & 63u], 1u);
        sorted[lo + pos] = (u16)(p >> 6);
    }
    if (b == 0 && rr == 0 && t == 0)
        offs[(size_t)nrel * N] = binbase_d[(size_t)nrel * NB];
}

// ---------- GEMM: h[rr] = (out_norm_rr * X) @ W[r0+rr], stored bf16 ----------
#define BM 64
#define BK 32
__global__ __launch_bounds__(256) void gemm_kernel(const float* __restrict__ X,
                                                   const float* __restrict__ W,
                                                   const float* __restrict__ out_normf,
                                                   u16* __restrict__ h, int N, int r0) {
    int rr = blockIdx.y;
    int r = r0 + rr;
    int row0 = blockIdx.x * BM;
    __shared__ float As[BK][BM + 1];
    __shared__ float Bs[BK][OUT_F];
    int t = threadIdx.x;
    int tx = t & 15, ty = t >> 4;
    float acc[4][8] = {};
    const float* Wr = W + (size_t)r * IN_F * OUT_F;
    const float* norm = out_normf + (size_t)rr * N;

    for (int k0 = 0; k0 < IN_F; k0 += BK) {
        #pragma unroll
        for (int l = 0; l < 2; l++) {
            int j = t + l * 256;
            int m = j >> 3, q = j & 7;
            int row = row0 + m;
            float4 v = make_float4(0.f, 0.f, 0.f, 0.f);
            float nv = 0.f;
            if (row < N) {
                v = *(const float4*)(X + (size_t)row * IN_F + k0 + q * 4);
                nv = norm[row];
            }
            As[q * 4 + 0][m] = v.x * nv;
            As[q * 4 + 1][m] = v.y * nv;
            As[q * 4 + 2][m] = v.z * nv;
            As[q * 4 + 3][m] = v.w * nv;
        }
        #pragma unroll
        for (int l = 0; l < 4; l++) {
            int j = t + l * 256;
            int k = j >> 5, q = j & 31;
            float4 v = *(const float4*)(Wr + (size_t)(k0 + k) * OUT_F + q * 4);
            *(float4*)&Bs[k][q * 4] = v;
        }
        __syncthreads();
        #pragma unroll
        for (int k = 0; k < BK; k++) {
            float a[4];
            #pragma unroll
            for (int i = 0; i < 4; i++) a[i] = As[k][ty * 4 + i];
            float4 b0 = *(float4*)&Bs[k][tx * 8];
            float4 b1 = *(float4*)&Bs[k][tx * 8 + 4];
            float bb[8] = {b0.x, b0.y, b0.z, b0.w, b1.x, b1.y, b1.z, b1.w};
            #pragma unroll
            for (int i = 0; i < 4; i++)
                #pragma unroll
                for (int jx = 0; jx < 8; jx++)
                    acc[i][jx] += a[i] * bb[jx];
        }
        __syncthreads();
    }
    u16* hr = h + (size_t)rr * N * OUT_F;
    #pragma unroll
    for (int i = 0; i < 4; i++) {
        int row = row0 + ty * 4 + i;
        if (row >= N) continue;
        u16 u[8];
        #pragma unroll
        for (int jx = 0; jx < 8; jx++) u[jx] = f32_to_bf16(acc[i][jx]);
        *(uint4*)(hr + (size_t)row * OUT_F + tx * 8) = *(uint4*)u;
    }
}

// ---------- aggregate: one wave per dst node, register-only accumulation ----------
__global__ __launch_bounds__(256) void aggregate_kernel(const u16* __restrict__ sorted,
                                                        const u32* __restrict__ offs,
                                                        const u16* __restrict__ h,
                                                        float* __restrict__ Z,
                                                        int N, int nrel, int accflag) {
    int wid = (blockIdx.x * 256 + threadIdx.x) >> 6;
    int lane = threadIdx.x & 63;
    if (wid >= N) return;
    float t0 = 0.f, t1 = 0.f;
    for (int rr = 0; rr < nrel; rr++) {
        u32 bi = offs[(size_t)rr * N + wid];
        u32 ei = offs[(size_t)rr * N + wid + 1];   // contiguous across bucket/relation joints
        const u32* hr = (const u32*)(h + (size_t)rr * N * OUT_F);   // 64 dwords per row
        float a0 = 0.f, a1 = 0.f;
        for (u32 i0 = bi; i0 < ei; i0 += 64u) {
            int m = (int)min(64u, ei - i0);
            u32 v = (lane < m) ? (u32)sorted[i0 + lane] : 0u;
            int j = 0;
            for (; j + 8 <= m; j += 8) {
                u32 rg[8];
                #pragma unroll
                for (int q = 0; q < 8; q++)
                    rg[q] = hr[(size_t)__shfl(v, j + q) * (OUT_F / 2) + lane];
                #pragma unroll
                for (int q = 0; q < 8; q++) { a0 += bf16lo(rg[q]); a1 += bf16hi(rg[q]); }
            }
            for (; j < m; j++) {
                u32 rv = hr[(size_t)__shfl(v, j) * (OUT_F / 2) + lane];
                a0 += bf16lo(rv); a1 += bf16hi(rv);
            }
        }
        float inr = rsqrtf((float)max(ei - bi, 1u));
        t0 += inr * a0;
        t1 += inr * a1;
    }
    float2* zp = (float2*)(Z + (size_t)wid * OUT_F + lane * 2);
    if (accflag) { float2 z = *zp; z.x += t0; z.y += t1; *zp = z; }
    else         { *zp = make_float2(t0, t1); }
}

// ---------- host ----------
extern "C" void kernel_launch(void* const* d_in, const int* in_sizes, int n_in,
                              void* d_out, int out_size, void* d_ws, size_t ws_size,
                              hipStream_t stream) {
    const float* X = (const float*)d_in[0];
    const float* W = (const float*)d_in[1];
    const int* EI = (const int*)d_in[2];
    float* Z = (float*)d_out;
    const int N = in_sizes[0] / IN_F;
    const int E = in_sizes[2] / (NUM_REL * 2);
    const int NB = (N + BN - 1) / BN;

    // persistent: sorted(u16), offs, out_norm, bbd, bbs, h(bf16)
    // transient (overlaid on h, all consumed before gemm writes h): ghd, ghs, bintot, part_dst, part_src
    size_t sorted_o, offs_o, out_norm_o, bbd_o, bbs_o, h_o, ghd_o, ghs_o, bintot_o, part_dst_o, part_src_o;
    auto layout = [&](int nb) -> size_t {
        size_t cur = 0;
        auto alloc = [&](size_t bytes) {
            size_t o = cur; cur = (cur + bytes + 255) & ~(size_t)255; return o;
        };
        int BINS = nb * NB;
        size_t TE = (size_t)nb * E;
        sorted_o   = alloc(TE * 2);
        offs_o     = alloc(((size_t)nb * N + 1) * 4);
        out_norm_o = alloc((size_t)nb * N * 4);
        bbd_o      = alloc((size_t)(BINS + 1) * 4);
        bbs_o      = alloc((size_t)(BINS + 1) * 4);
        h_o        = alloc((size_t)nb * N * OUT_F * 2);
        size_t hend = cur;
        size_t ov = h_o;
        auto oalloc = [&](size_t bytes) {
            size_t o = ov; ov = (ov + bytes + 255) & ~(size_t)255; return o;
        };
        ghd_o      = oalloc((size_t)BINS * PBX * 4);
        ghs_o      = oalloc((size_t)BINS * PBX * 4);
        bintot_o   = oalloc((size_t)2 * BINS * 4);
        part_dst_o = oalloc(TE * 4);
        part_src_o = oalloc(TE);
        return (ov > hend) ? ov : hend;
    };
    int nb = NUM_REL;
    while (nb > 1 && layout(nb) > ws_size) nb >>= 1;
    layout(nb);
    char* ws = (char*)d_ws;
    const int nbatches = (NUM_REL + nb - 1) / nb;

    if (nbatches > 1)
        hipMemsetAsync(d_out, 0, (size_t)N * OUT_F * sizeof(float), stream);

    for (int r0 = 0; r0 < NUM_REL; r0 += nb) {
        int cur = min(nb, NUM_REL - r0);
        int BINS = cur * NB;
        u16* sorted   = (u16*)(ws + sorted_o);
        u32* offs     = (u32*)(ws + offs_o);
        float* out_norm = (float*)(ws + out_norm_o);
        u32* bbd      = (u32*)(ws + bbd_o);
        u32* bbs      = (u32*)(ws + bbs_o);
        u16* h        = (u16*)(ws + h_o);
        u32* ghd      = (u32*)(ws + ghd_o);
        u32* ghs      = (u32*)(ws + ghs_o);
        u32* bintot   = (u32*)(ws + bintot_o);
        u32* part_dst = (u32*)(ws + part_dst_o);
        u8* part_src  = (u8*)(ws + part_src_o);

        p1_hist<<<dim3(PBX, cur), PT, 2 * NB * 4, stream>>>(EI, ghd, ghs, E, NB, r0);
        p2a_scan<<<(2 * BINS + 3) / 4, 256, 0, stream>>>(ghd, ghs, bintot, BINS);
        p2b_scan<<<1, 1024, 0, stream>>>(bintot, bbd, bbs, BINS);
        p3_scatter<<<dim3(PBX, cur), PT, 4 * NB * 4, stream>>>(
            EI, ghd, ghs, bbd, bbs, part_dst, part_src, E, NB, r0);
        srccount_kernel<<<dim3(NB, cur), 256, 0, stream>>>(part_src, bbs, out_norm, N, NB);
        p4_sort<<<dim3(NB, cur), 256, 0, stream>>>(part_dst, bbd, offs, sorted, N, NB, cur);
        gemm_kernel<<<dim3((N + BM - 1) / BM, cur), 256, 0, stream>>>(X, W, out_norm, h, N, r0);
        aggregate_kernel<<<((size_t)N * 64 + 255) / 256, 256, 0, stream>>>(
            sorted, offs, h, Z, N, cur, (nbatches > 1) ? 1 : 0);
    }
}

// Round 4
// 472.508 us; speedup vs baseline: 12.7070x; 1.2646x over previous
//
#include <hip/hip_runtime.h>

#define IN_F 256
#define OUT_F 128
#define NUM_REL 4
#define BN 64      // nodes per bucket
#define PBX 64     // partition blocks per relation (must be 64: wave-scan width)
#define PT 512     // partition block threads

typedef unsigned int u32;
typedef unsigned short u16;
typedef unsigned char u8;

typedef __attribute__((ext_vector_type(8))) short bf16x8;
typedef __attribute__((ext_vector_type(4))) float f32x4;

static __device__ __forceinline__ u16 f32_to_bf16(float f) {
    union { float f; u32 u; } c; c.f = f;
    u32 u = c.u;
    u32 r = (u + 0x7fffu + ((u >> 16) & 1u)) >> 16;   // RNE
    return (u16)r;
}
static __device__ __forceinline__ float bf16lo(u32 v) {
    union { u32 u; float f; } c; c.u = v << 16; return c.f;
}
static __device__ __forceinline__ float bf16hi(u32 v) {
    union { u32 u; float f; } c; c.u = v & 0xffff0000u; return c.f;
}

// ---------- P1: per-block LDS histograms over dst-buckets and src-buckets ----------
__global__ __launch_bounds__(PT) void p1_hist(const int* __restrict__ EI, u32* __restrict__ ghd,
                                              u32* __restrict__ ghs, int E, int NB, int r0) {
    int rr = blockIdx.y, x = blockIdx.x;
    int r = r0 + rr;
    const int* src = EI + (size_t)(2 * r) * E;
    const int* dst = src + E;
    extern __shared__ u32 sh[];           // hd[NB], hs[NB]
    u32* hd = sh; u32* hs = sh + NB;
    for (int i = threadIdx.x; i < 2 * NB; i += PT) sh[i] = 0;
    __syncthreads();
    int CH = (E + PBX - 1) / PBX;
    int lo = x * CH, hi = min(E, lo + CH);
    for (int e = lo + threadIdx.x; e < hi; e += PT) {
        atomicAdd(&hd[dst[e] >> 6], 1u);
        atomicAdd(&hs[src[e] >> 6], 1u);
    }
    __syncthreads();
    for (int b = threadIdx.x; b < NB; b += PT) {
        ghd[(size_t)(rr * NB + b) * PBX + x] = hd[b];
        ghs[(size_t)(rr * NB + b) * PBX + x] = hs[b];
    }
}

// ---------- P2a: per-bin exclusive scan over the PBX=64 block columns (one wave per bin) ----------
__global__ __launch_bounds__(256) void p2a_scan(u32* __restrict__ ghd, u32* __restrict__ ghs,
                                                u32* __restrict__ bintot, int BINS) {
    int wid = blockIdx.x * 4 + (threadIdx.x >> 6);
    int lane = threadIdx.x & 63;
    if (wid >= 2 * BINS) return;
    u32* g = (wid < BINS) ? ghd : ghs;
    int bin = (wid < BINS) ? wid : wid - BINS;
    u32 c = g[(size_t)bin * PBX + lane];
    u32 xv = c;
    #pragma unroll
    for (int s = 1; s < 64; s <<= 1) {
        u32 y = __shfl_up(xv, s);
        if (lane >= s) xv += y;
    }
    g[(size_t)bin * PBX + lane] = xv - c;       // exclusive within bin
    if (lane == 63) bintot[wid] = xv;           // bin total
}

// ---------- P2b: exclusive scan over bins (two segments: dst then src) ----------
__global__ __launch_bounds__(1024) void p2b_scan(const u32* __restrict__ bintot,
                                                 u32* __restrict__ binbase_d,
                                                 u32* __restrict__ binbase_s, int BINS) {
    __shared__ u32 s[1024];
    __shared__ u32 carry;
    int t = threadIdx.x;
    for (int seg = 0; seg < 2; seg++) {
        const u32* in = bintot + (size_t)seg * BINS;
        u32* out = seg ? binbase_s : binbase_d;
        if (t == 0) carry = 0;
        __syncthreads();
        for (int base = 0; base < BINS; base += 1024) {
            int i = base + t;
            u32 v = (i < BINS) ? in[i] : 0;
            s[t] = v;
            __syncthreads();
            for (int off = 1; off < 1024; off <<= 1) {
                u32 x = (t >= off) ? s[t - off] : 0;
                __syncthreads();
                s[t] += x;
                __syncthreads();
            }
            u32 incl = s[t]; u32 c0 = carry;
            if (i < BINS) out[i] = c0 + incl - v;
            __syncthreads();
            if (t == 1023) carry = c0 + incl;
            __syncthreads();
        }
        if (t == 0) out[BINS] = carry;
        __syncthreads();
    }
}

// ---------- P3: atomic-free (global) scatter into bucketed pools ----------
__global__ __launch_bounds__(PT) void p3_scatter(const int* __restrict__ EI,
                                                 const u32* __restrict__ ghd, const u32* __restrict__ ghs,
                                                 const u32* __restrict__ binbase_d, const u32* __restrict__ binbase_s,
                                                 u32* __restrict__ part_dst, u8* __restrict__ part_src,
                                                 int E, int NB, int r0) {
    int rr = blockIdx.y, x = blockIdx.x;
    int r = r0 + rr;
    const int* src = EI + (size_t)(2 * r) * E;
    const int* dst = src + E;
    extern __shared__ u32 sh[];           // base_d[NB] cur_d[NB] base_s[NB] cur_s[NB]
    u32* base_d = sh; u32* cur_d = sh + NB; u32* base_s = sh + 2 * NB; u32* cur_s = sh + 3 * NB;
    for (int b = threadIdx.x; b < NB; b += PT) {
        int bin = rr * NB + b;
        base_d[b] = binbase_d[bin] + ghd[(size_t)bin * PBX + x];
        base_s[b] = binbase_s[bin] + ghs[(size_t)bin * PBX + x];
        cur_d[b] = 0; cur_s[b] = 0;
    }
    __syncthreads();
    int CH = (E + PBX - 1) / PBX;
    int lo = x * CH, hi = min(E, lo + CH);
    for (int e = lo + threadIdx.x; e < hi; e += PT) {
        int sv = src[e], dv = dst[e];
        int db = dv >> 6, sb = sv >> 6;
        u32 rk = atomicAdd(&cur_d[db], 1u);
        part_dst[base_d[db] + rk] = ((u32)sv << 6) | (u32)(dv & 63);
        u32 rk2 = atomicAdd(&cur_s[sb], 1u);
        part_src[base_s[sb] + rk2] = (u8)(sv & 63);
    }
}

// ---------- out-degree count per src bucket -> out_norm ----------
__global__ __launch_bounds__(256) void srccount_kernel(const u8* __restrict__ part_src,
                                                       const u32* __restrict__ binbase_s,
                                                       float* __restrict__ out_norm, int N, int NB) {
    int b = blockIdx.x, rr = blockIdx.y;
    int bin = rr * NB + b;
    __shared__ u32 cnt[BN];
    int t = threadIdx.x;
    if (t < BN) cnt[t] = 0;
    __syncthreads();
    u32 lo = binbase_s[bin], hi = binbase_s[bin + 1];
    for (u32 i = lo + t; i < hi; i += 256) atomicAdd(&cnt[part_src[i]], 1u);
    __syncthreads();
    if (t < BN) {
        int node = b * BN + t;
        if (node < N) out_norm[(size_t)rr * N + node] = rsqrtf((float)max(cnt[t], 1u));
    }
}

// ---------- P4: within-bucket counting sort -> full per-node CSR (offsets + u16 src list) ----------
__global__ __launch_bounds__(256) void p4_sort(const u32* __restrict__ part_dst,
                                               const u32* __restrict__ binbase_d,
                                               u32* __restrict__ offs, u16* __restrict__ sorted,
                                               int N, int NB, int nrel) {
    int b = blockIdx.x, rr = blockIdx.y;
    int bin = rr * NB + b;
    __shared__ u32 cnt[BN];
    int t = threadIdx.x;
    if (t < BN) cnt[t] = 0;
    __syncthreads();
    u32 lo = binbase_d[bin], hi = binbase_d[bin + 1];
    for (u32 i = lo + t; i < hi; i += 256) atomicAdd(&cnt[part_dst[i] & 63u], 1u);
    __syncthreads();
    if (t < BN) {
        u32 c = cnt[t];
        u32 x = c;
        #pragma unroll
        for (int s = 1; s < 64; s <<= 1) {
            u32 y = __shfl_up(x, s);
            if (t >= s) x += y;
        }
        u32 excl = x - c;
        int node = b * BN + t;
        if (node < N) offs[(size_t)rr * N + node] = lo + excl;
        cnt[t] = excl;                    // becomes the scatter cursor
    }
    __syncthreads();
    for (u32 i = lo + t; i < hi; i += 256) {
        u32 p = part_dst[i];
        u32 pos = atomicAdd(&cnt[p & 63u], 1u);
        sorted[lo + pos] = (u16)(p >> 6);
    }
    if (b == 0 && rr == 0 && t == 0)
        offs[(size_t)nrel * N] = binbase_d[(size_t)nrel * NB];
}

// ---------- W fragment-image: BImg chunk q = ng*512 + kg*16 + c holds W[8kg+j][16ng+c], j=0..7 ----------
__global__ void wt_kernel(const float* __restrict__ W, u16* __restrict__ BImg, int nrel) {
    int idx = blockIdx.x * 256 + threadIdx.x;
    if (idx >= nrel * 4096) return;
    int r = idx >> 12, q = idx & 4095;
    int ng = q >> 9, kg = (q >> 4) & 31, c = q & 15;
    const float* Wr = W + (size_t)r * IN_F * OUT_F;
    u16 o[8];
    #pragma unroll
    for (int j = 0; j < 8; j++)
        o[j] = f32_to_bf16(Wr[(size_t)(8 * kg + j) * OUT_F + 16 * ng + c]);
    *(uint4*)(BImg + (size_t)idx * 8) = *(const uint4*)o;
}

// ---------- X fragment-image (bf16, unscaled): flat chunk = (R*4+S)*1024 + mg*128+kgl*16+rw ----------
__global__ void xb_kernel(const float* __restrict__ X, u16* __restrict__ Xb, int N, int nchunks) {
    int idx = blockIdx.x * 256 + threadIdx.x;
    if (idx >= nchunks) return;
    int ci = idx & 1023;
    int S = (idx >> 10) & 3;
    int R = idx >> 12;
    int mg = ci >> 7, kgl = (ci >> 4) & 7, rw = ci & 15;
    int row = R * 128 + mg * 16 + rw;
    int k0 = S * 64 + kgl * 8;
    u16 o[8] = {0, 0, 0, 0, 0, 0, 0, 0};
    if (row < N) {
        const float* xp = X + (size_t)row * IN_F + k0;
        float4 v0 = *(const float4*)xp;
        float4 v1 = *(const float4*)(xp + 4);
        o[0] = f32_to_bf16(v0.x); o[1] = f32_to_bf16(v0.y);
        o[2] = f32_to_bf16(v0.z); o[3] = f32_to_bf16(v0.w);
        o[4] = f32_to_bf16(v1.x); o[5] = f32_to_bf16(v1.y);
        o[6] = f32_to_bf16(v1.z); o[7] = f32_to_bf16(v1.w);
    }
    *(uint4*)(Xb + (size_t)idx * 8) = *(const uint4*)o;
}

// ---------- MFMA GEMM: h[rr] = bf16( out_norm ⊙ (X @ W[r]) ) ----------
// 128x128 tile, 4 waves (2x2 of 64x64), BK=64, whole W[r] in LDS, A single-buffered + reg prefetch.
__global__ __launch_bounds__(256) void gemm_kernel(const u16* __restrict__ Xb,
                                                   const u16* __restrict__ BImg,
                                                   const float* __restrict__ out_norm,
                                                   u16* __restrict__ h, int N, int r0) {
    int rr = blockIdx.y;
    int r = r0 + rr;
    int R = blockIdx.x;
    int row0 = R * 128;
    __shared__ short Alds[8192];    // 16 KB (one BK=64 step, fragment layout)
    __shared__ short Blds[32768];   // 64 KB (whole W[r], fragment layout)
    int t = threadIdx.x;
    int lane = t & 63, w = t >> 6;
    int wm = w >> 1, wn = w & 1;

    // stage whole B image (4096 chunks of 16B)
    const uint4* bsrc = (const uint4*)(BImg + (size_t)r * 32768);
    uint4* bdst = (uint4*)Blds;
    #pragma unroll
    for (int i = 0; i < 16; i++) bdst[i * 256 + t] = bsrc[i * 256 + t];

    f32x4 acc[4][4];
    #pragma unroll
    for (int mi = 0; mi < 4; mi++)
        #pragma unroll
        for (int ni = 0; ni < 4; ni++) acc[mi][ni] = (f32x4){0.f, 0.f, 0.f, 0.f};

    const uint4* xb4 = (const uint4*)Xb + (size_t)R * 4096;
    uint4 areg[4];
    #pragma unroll
    for (int i = 0; i < 4; i++) areg[i] = xb4[i * 256 + t];   // K-step 0

    for (int S = 0; S < 4; S++) {
        uint4* adst = (uint4*)Alds;
        #pragma unroll
        for (int i = 0; i < 4; i++) adst[i * 256 + t] = areg[i];
        __syncthreads();
        if (S < 3) {
            #pragma unroll
            for (int i = 0; i < 4; i++) areg[i] = xb4[(size_t)(S + 1) * 1024 + i * 256 + t];
        }
        #pragma unroll
        for (int kf = 0; kf < 2; kf++) {
            bf16x8 a[4], b[4];
            #pragma unroll
            for (int mi = 0; mi < 4; mi++)
                a[mi] = *(const bf16x8*)(Alds + (wm * 4 + mi) * 1024 + kf * 512 + lane * 8);
            #pragma unroll
            for (int ni = 0; ni < 4; ni++)
                b[ni] = *(const bf16x8*)(Blds + (wn * 4 + ni) * 4096 + S * 1024 + kf * 512 + lane * 8);
            #pragma unroll
            for (int mi = 0; mi < 4; mi++)
                #pragma unroll
                for (int ni = 0; ni < 4; ni++)
                    acc[mi][ni] = __builtin_amdgcn_mfma_f32_16x16x32_bf16(a[mi], b[ni], acc[mi][ni], 0, 0, 0);
        }
        __syncthreads();
    }

    // epilogue: scale by out_norm[row], convert, store (C/D: col=lane&15, row=(lane>>4)*4+reg)
    const float* nrm = out_norm + (size_t)rr * N;
    u16* hr = h + (size_t)rr * N * OUT_F;
    #pragma unroll
    for (int mi = 0; mi < 4; mi++) {
        #pragma unroll
        for (int rg = 0; rg < 4; rg++) {
            int row = row0 + wm * 64 + mi * 16 + (lane >> 4) * 4 + rg;
            if (row >= N) continue;
            float nv = nrm[row];
            #pragma unroll
            for (int ni = 0; ni < 4; ni++) {
                int col = wn * 64 + ni * 16 + (lane & 15);
                hr[(size_t)row * OUT_F + col] = f32_to_bf16(acc[mi][ni][rg] * nv);
            }
        }
    }
}

// ---------- aggregate: one wave per dst node, register-only accumulation ----------
__global__ __launch_bounds__(256) void aggregate_kernel(const u16* __restrict__ sorted,
                                                        const u32* __restrict__ offs,
                                                        const u16* __restrict__ h,
                                                        float* __restrict__ Z,
                                                        int N, int nrel, int accflag) {
    int wid = (blockIdx.x * 256 + threadIdx.x) >> 6;
    int lane = threadIdx.x & 63;
    if (wid >= N) return;
    float t0 = 0.f, t1 = 0.f;
    for (int rr = 0; rr < nrel; rr++) {
        u32 bi = offs[(size_t)rr * N + wid];
        u32 ei = offs[(size_t)rr * N + wid + 1];   // contiguous across bucket/relation joints
        const u32* hr = (const u32*)(h + (size_t)rr * N * OUT_F);   // 64 dwords per row
        float a0 = 0.f, a1 = 0.f;
        for (u32 i0 = bi; i0 < ei; i0 += 64u) {
            int m = (int)min(64u, ei - i0);
            u32 v = (lane < m) ? (u32)sorted[i0 + lane] : 0u;
            int j = 0;
            for (; j + 8 <= m; j += 8) {
                u32 rg[8];
                #pragma unroll
                for (int q = 0; q < 8; q++)
                    rg[q] = hr[(size_t)__shfl(v, j + q) * (OUT_F / 2) + lane];
                #pragma unroll
                for (int q = 0; q < 8; q++) { a0 += bf16lo(rg[q]); a1 += bf16hi(rg[q]); }
            }
            for (; j < m; j++) {
                u32 rv = hr[(size_t)__shfl(v, j) * (OUT_F / 2) + lane];
                a0 += bf16lo(rv); a1 += bf16hi(rv);
            }
        }
        float inr = rsqrtf((float)max(ei - bi, 1u));
        t0 += inr * a0;
        t1 += inr * a1;
    }
    float2* zp = (float2*)(Z + (size_t)wid * OUT_F + lane * 2);
    if (accflag) { float2 z = *zp; z.x += t0; z.y += t1; *zp = z; }
    else         { *zp = make_float2(t0, t1); }
}

// ---------- host ----------
extern "C" void kernel_launch(void* const* d_in, const int* in_sizes, int n_in,
                              void* d_out, int out_size, void* d_ws, size_t ws_size,
                              hipStream_t stream) {
    const float* X = (const float*)d_in[0];
    const float* W = (const float*)d_in[1];
    const int* EI = (const int*)d_in[2];
    float* Z = (float*)d_out;
    const int N = in_sizes[0] / IN_F;
    const int E = in_sizes[2] / (NUM_REL * 2);
    const int NB = (N + BN - 1) / BN;
    const int RBcnt = (N + 127) / 128;

    // persistent: sorted, offs, out_norm, bbd, bbs, xb, bimg, h
    // transient (overlaid on h region, all consumed before gemm writes h): ghd, ghs, bintot, part_dst, part_src
    size_t sorted_o, offs_o, out_norm_o, bbd_o, bbs_o, xb_o, bimg_o, h_o,
           ghd_o, ghs_o, bintot_o, part_dst_o, part_src_o;
    auto layout = [&](int nb) -> size_t {
        size_t cur = 0;
        auto alloc = [&](size_t bytes) {
            size_t o = cur; cur = (cur + bytes + 255) & ~(size_t)255; return o;
        };
        int BINS = nb * NB;
        size_t TE = (size_t)nb * E;
        sorted_o   = alloc(TE * 2);
        offs_o     = alloc(((size_t)nb * N + 1) * 4);
        out_norm_o = alloc((size_t)nb * N * 4);
        bbd_o      = alloc((size_t)(BINS + 1) * 4);
        bbs_o      = alloc((size_t)(BINS + 1) * 4);
        xb_o       = alloc((size_t)RBcnt * 4096 * 16);
        bimg_o     = alloc((size_t)NUM_REL * 4096 * 16);
        h_o        = alloc((size_t)nb * N * OUT_F * 2);
        size_t hend = cur;
        size_t ov = h_o;
        auto oalloc = [&](size_t bytes) {
            size_t o = ov; ov = (ov + bytes + 255) & ~(size_t)255; return o;
        };
        ghd_o      = oalloc((size_t)BINS * PBX * 4);
        ghs_o      = oalloc((size_t)BINS * PBX * 4);
        bintot_o   = oalloc((size_t)2 * BINS * 4);
        part_dst_o = oalloc(TE * 4);
        part_src_o = oalloc(TE);
        return (ov > hend) ? ov : hend;
    };
    int nb = NUM_REL;
    while (nb > 1 && layout(nb) > ws_size) nb >>= 1;
    layout(nb);
    char* ws = (char*)d_ws;
    const int nbatches = (NUM_REL + nb - 1) / nb;

    u16* xb = (u16*)(ws + xb_o);
    u16* bimg = (u16*)(ws + bimg_o);

    // one-time fragment-image prep (independent of the partition pipeline)
    int nchunks = RBcnt * 4096;
    xb_kernel<<<(nchunks + 255) / 256, 256, 0, stream>>>(X, xb, N, nchunks);
    wt_kernel<<<(NUM_REL * 4096 + 255) / 256, 256, 0, stream>>>(W, bimg, NUM_REL);

    if (nbatches > 1)
        hipMemsetAsync(d_out, 0, (size_t)N * OUT_F * sizeof(float), stream);

    for (int r0 = 0; r0 < NUM_REL; r0 += nb) {
        int cur = min(nb, NUM_REL - r0);
        int BINS = cur * NB;
        u16* sorted   = (u16*)(ws + sorted_o);
        u32* offs     = (u32*)(ws + offs_o);
        float* out_norm = (float*)(ws + out_norm_o);
        u32* bbd      = (u32*)(ws + bbd_o);
        u32* bbs      = (u32*)(ws + bbs_o);
        u16* h        = (u16*)(ws + h_o);
        u32* ghd      = (u32*)(ws + ghd_o);
        u32* ghs      = (u32*)(ws + ghs_o);
        u32* bintot   = (u32*)(ws + bintot_o);
        u32* part_dst = (u32*)(ws + part_dst_o);
        u8* part_src  = (u8*)(ws + part_src_o);

        p1_hist<<<dim3(PBX, cur), PT, 2 * NB * 4, stream>>>(EI, ghd, ghs, E, NB, r0);
        p2a_scan<<<(2 * BINS + 3) / 4, 256, 0, stream>>>(ghd, ghs, bintot, BINS);
        p2b_scan<<<1, 1024, 0, stream>>>(bintot, bbd, bbs, BINS);
        p3_scatter<<<dim3(PBX, cur), PT, 4 * NB * 4, stream>>>(
            EI, ghd, ghs, bbd, bbs, part_dst, part_src, E, NB, r0);
        srccount_kernel<<<dim3(NB, cur), 256, 0, stream>>>(part_src, bbs, out_norm, N, NB);
        p4_sort<<<dim3(NB, cur), 256, 0, stream>>>(part_dst, bbd, offs, sorted, N, NB, cur);
        gemm_kernel<<<dim3(RBcnt, cur), 256, 0, stream>>>(xb, bimg, out_norm, h, N, r0);
        aggregate_kernel<<<((size_t)N * 64 + 255) / 256, 256, 0, stream>>>(
            sorted, offs, h, Z, N, cur, (nbatches > 1) ? 1 : 0);
    }
}

// Round 5
// 461.460 us; speedup vs baseline: 13.0112x; 1.0239x over previous
//
#include <hip/hip_runtime.h>

#define IN_F 256
#define OUT_F 128
#define NUM_REL 4
#define BN 64      // nodes per bucket
#define PBX 64     // partition blocks per relation (must be 64: wave-scan width)
#define PT 512     // partition block threads

typedef unsigned int u32;
typedef unsigned short u16;
typedef unsigned char u8;

typedef __attribute__((ext_vector_type(8))) short bf16x8;
typedef __attribute__((ext_vector_type(4))) float f32x4;

static __device__ __forceinline__ u16 f32_to_bf16(float f) {
    union { float f; u32 u; } c; c.f = f;
    u32 u = c.u;
    u32 r = (u + 0x7fffu + ((u >> 16) & 1u)) >> 16;   // RNE
    return (u16)r;
}
static __device__ __forceinline__ float bf16lo(u32 v) {
    union { u32 u; float f; } c; c.u = v << 16; return c.f;
}
static __device__ __forceinline__ float bf16hi(u32 v) {
    union { u32 u; float f; } c; c.u = v & 0xffff0000u; return c.f;
}

// ---------- P1: per-block LDS histograms over dst-buckets and src-buckets ----------
__global__ __launch_bounds__(PT) void p1_hist(const int* __restrict__ EI, u32* __restrict__ ghd,
                                              u32* __restrict__ ghs, int E, int NB, int r0) {
    int rr = blockIdx.y, x = blockIdx.x;
    int r = r0 + rr;
    const int* src = EI + (size_t)(2 * r) * E;
    const int* dst = src + E;
    extern __shared__ u32 sh[];           // hd[NB], hs[NB]
    u32* hd = sh; u32* hs = sh + NB;
    for (int i = threadIdx.x; i < 2 * NB; i += PT) sh[i] = 0;
    __syncthreads();
    int CH = (E + PBX - 1) / PBX;
    int lo = x * CH, hi = min(E, lo + CH);
    for (int e = lo + threadIdx.x; e < hi; e += PT) {
        atomicAdd(&hd[dst[e] >> 6], 1u);
        atomicAdd(&hs[src[e] >> 6], 1u);
    }
    __syncthreads();
    for (int b = threadIdx.x; b < NB; b += PT) {
        ghd[(size_t)(rr * NB + b) * PBX + x] = hd[b];
        ghs[(size_t)(rr * NB + b) * PBX + x] = hs[b];
    }
}

// ---------- P2a: per-bin exclusive scan over the PBX=64 block columns (one wave per bin) ----------
__global__ __launch_bounds__(256) void p2a_scan(u32* __restrict__ ghd, u32* __restrict__ ghs,
                                                u32* __restrict__ bintot, int BINS) {
    int wid = blockIdx.x * 4 + (threadIdx.x >> 6);
    int lane = threadIdx.x & 63;
    if (wid >= 2 * BINS) return;
    u32* g = (wid < BINS) ? ghd : ghs;
    int bin = (wid < BINS) ? wid : wid - BINS;
    u32 c = g[(size_t)bin * PBX + lane];
    u32 xv = c;
    #pragma unroll
    for (int s = 1; s < 64; s <<= 1) {
        u32 y = __shfl_up(xv, s);
        if (lane >= s) xv += y;
    }
    g[(size_t)bin * PBX + lane] = xv - c;       // exclusive within bin
    if (lane == 63) bintot[wid] = xv;           // bin total
}

// ---------- P2b: exclusive scan over bins (two segments: dst then src) ----------
__global__ __launch_bounds__(1024) void p2b_scan(const u32* __restrict__ bintot,
                                                 u32* __restrict__ binbase_d,
                                                 u32* __restrict__ binbase_s, int BINS) {
    __shared__ u32 s[1024];
    __shared__ u32 carry;
    int t = threadIdx.x;
    for (int seg = 0; seg < 2; seg++) {
        const u32* in = bintot + (size_t)seg * BINS;
        u32* out = seg ? binbase_s : binbase_d;
        if (t == 0) carry = 0;
        __syncthreads();
        for (int base = 0; base < BINS; base += 1024) {
            int i = base + t;
            u32 v = (i < BINS) ? in[i] : 0;
            s[t] = v;
            __syncthreads();
            for (int off = 1; off < 1024; off <<= 1) {
                u32 x = (t >= off) ? s[t - off] : 0;
                __syncthreads();
                s[t] += x;
                __syncthreads();
            }
            u32 incl = s[t]; u32 c0 = carry;
            if (i < BINS) out[i] = c0 + incl - v;
            __syncthreads();
            if (t == 1023) carry = c0 + incl;
            __syncthreads();
        }
        if (t == 0) out[BINS] = carry;
        __syncthreads();
    }
}

// ---------- P3: atomic-free (global) scatter into bucketed pools ----------
__global__ __launch_bounds__(PT) void p3_scatter(const int* __restrict__ EI,
                                                 const u32* __restrict__ ghd, const u32* __restrict__ ghs,
                                                 const u32* __restrict__ binbase_d, const u32* __restrict__ binbase_s,
                                                 u32* __restrict__ part_dst, u8* __restrict__ part_src,
                                                 int E, int NB, int r0) {
    int rr = blockIdx.y, x = blockIdx.x;
    int r = r0 + rr;
    const int* src = EI + (size_t)(2 * r) * E;
    const int* dst = src + E;
    extern __shared__ u32 sh[];           // base_d[NB] cur_d[NB] base_s[NB] cur_s[NB]
    u32* base_d = sh; u32* cur_d = sh + NB; u32* base_s = sh + 2 * NB; u32* cur_s = sh + 3 * NB;
    for (int b = threadIdx.x; b < NB; b += PT) {
        int bin = rr * NB + b;
        base_d[b] = binbase_d[bin] + ghd[(size_t)bin * PBX + x];
        base_s[b] = binbase_s[bin] + ghs[(size_t)bin * PBX + x];
        cur_d[b] = 0; cur_s[b] = 0;
    }
    __syncthreads();
    int CH = (E + PBX - 1) / PBX;
    int lo = x * CH, hi = min(E, lo + CH);
    for (int e = lo + threadIdx.x; e < hi; e += PT) {
        int sv = src[e], dv = dst[e];
        int db = dv >> 6, sb = sv >> 6;
        u32 rk = atomicAdd(&cur_d[db], 1u);
        part_dst[base_d[db] + rk] = ((u32)sv << 6) | (u32)(dv & 63);
        u32 rk2 = atomicAdd(&cur_s[sb], 1u);
        part_src[base_s[sb] + rk2] = (u8)(sv & 63);
    }
}

// ---------- out-degree count per src bucket -> out_norm ----------
__global__ __launch_bounds__(256) void srccount_kernel(const u8* __restrict__ part_src,
                                                       const u32* __restrict__ binbase_s,
                                                       float* __restrict__ out_norm, int N, int NB) {
    int b = blockIdx.x, rr = blockIdx.y;
    int bin = rr * NB + b;
    __shared__ u32 cnt[BN];
    int t = threadIdx.x;
    if (t < BN) cnt[t] = 0;
    __syncthreads();
    u32 lo = binbase_s[bin], hi = binbase_s[bin + 1];
    for (u32 i = lo + t; i < hi; i += 256) atomicAdd(&cnt[part_src[i]], 1u);
    __syncthreads();
    if (t < BN) {
        int node = b * BN + t;
        if (node < N) out_norm[(size_t)rr * N + node] = rsqrtf((float)max(cnt[t], 1u));
    }
}

// ---------- P4: within-bucket counting sort -> full per-node CSR (offsets + u16 src list) ----------
__global__ __launch_bounds__(256) void p4_sort(const u32* __restrict__ part_dst,
                                               const u32* __restrict__ binbase_d,
                                               u32* __restrict__ offs, u16* __restrict__ sorted,
                                               int N, int NB, int nrel) {
    int b = blockIdx.x, rr = blockIdx.y;
    int bin = rr * NB + b;
    __shared__ u32 cnt[BN];
    int t = threadIdx.x;
    if (t < BN) cnt[t] = 0;
    __syncthreads();
    u32 lo = binbase_d[bin], hi = binbase_d[bin + 1];
    for (u32 i = lo + t; i < hi; i += 256) atomicAdd(&cnt[part_dst[i] & 63u], 1u);
    __syncthreads();
    if (t < BN) {
        u32 c = cnt[t];
        u32 x = c;
        #pragma unroll
        for (int s = 1; s < 64; s <<= 1) {
            u32 y = __shfl_up(x, s);
            if (t >= s) x += y;
        }
        u32 excl = x - c;
        int node = b * BN + t;
        if (node < N) offs[(size_t)rr * N + node] = lo + excl;
        cnt[t] = excl;                    // becomes the scatter cursor
    }
    __syncthreads();
    for (u32 i = lo + t; i < hi; i += 256) {
        u32 p = part_dst[i];
        u32 pos = atomicAdd(&cnt[p & 63u], 1u);
        sorted[lo + pos] = (u16)(p >> 6);
    }
    if (b == 0 && rr == 0 && t == 0)
        offs[(size_t)nrel * N] = binbase_d[(size_t)nrel * NB];
}

// ---------- W fragment-image: BImg chunk q = ng*512 + kg*16 + c holds W[8kg+j][16ng+c], j=0..7 ----------
__global__ void wt_kernel(const float* __restrict__ W, u16* __restrict__ BImg, int nrel) {
    int idx = blockIdx.x * 256 + threadIdx.x;
    if (idx >= nrel * 4096) return;
    int r = idx >> 12, q = idx & 4095;
    int ng = q >> 9, kg = (q >> 4) & 31, c = q & 15;
    const float* Wr = W + (size_t)r * IN_F * OUT_F;
    u16 o[8];
    #pragma unroll
    for (int j = 0; j < 8; j++)
        o[j] = f32_to_bf16(Wr[(size_t)(8 * kg + j) * OUT_F + 16 * ng + c]);
    *(uint4*)(BImg + (size_t)idx * 8) = *(const uint4*)o;
}

// ---------- X fragment-image (bf16, unscaled): flat chunk = (R*4+S)*1024 + mg*128+kgl*16+rw ----------
__global__ void xb_kernel(const float* __restrict__ X, u16* __restrict__ Xb, int N, int nchunks) {
    int idx = blockIdx.x * 256 + threadIdx.x;
    if (idx >= nchunks) return;
    int ci = idx & 1023;
    int S = (idx >> 10) & 3;
    int R = idx >> 12;
    int mg = ci >> 7, kgl = (ci >> 4) & 7, rw = ci & 15;
    int row = R * 128 + mg * 16 + rw;
    int k0 = S * 64 + kgl * 8;
    u16 o[8] = {0, 0, 0, 0, 0, 0, 0, 0};
    if (row < N) {
        const float* xp = X + (size_t)row * IN_F + k0;
        float4 v0 = *(const float4*)xp;
        float4 v1 = *(const float4*)(xp + 4);
        o[0] = f32_to_bf16(v0.x); o[1] = f32_to_bf16(v0.y);
        o[2] = f32_to_bf16(v0.z); o[3] = f32_to_bf16(v0.w);
        o[4] = f32_to_bf16(v1.x); o[5] = f32_to_bf16(v1.y);
        o[6] = f32_to_bf16(v1.z); o[7] = f32_to_bf16(v1.w);
    }
    *(uint4*)(Xb + (size_t)idx * 8) = *(const uint4*)o;
}

// ---------- MFMA GEMM: h[rr] = bf16( out_norm ⊙ (X @ W[r]) ) ----------
// 128x128 tile, 4 waves (2x2 of 64x64), BK=64, whole W[r] in LDS, A single-buffered + reg prefetch.
__global__ __launch_bounds__(256) void gemm_kernel(const u16* __restrict__ Xb,
                                                   const u16* __restrict__ BImg,
                                                   const float* __restrict__ out_norm,
                                                   u16* __restrict__ h, int N, int r0) {
    int rr = blockIdx.y;
    int r = r0 + rr;
    int R = blockIdx.x;
    int row0 = R * 128;
    __shared__ short Alds[8192];    // 16 KB (one BK=64 step, fragment layout)
    __shared__ short Blds[32768];   // 64 KB (whole W[r], fragment layout)
    int t = threadIdx.x;
    int lane = t & 63, w = t >> 6;
    int wm = w >> 1, wn = w & 1;

    // stage whole B image (4096 chunks of 16B)
    const uint4* bsrc = (const uint4*)(BImg + (size_t)r * 32768);
    uint4* bdst = (uint4*)Blds;
    #pragma unroll
    for (int i = 0; i < 16; i++) bdst[i * 256 + t] = bsrc[i * 256 + t];

    f32x4 acc[4][4];
    #pragma unroll
    for (int mi = 0; mi < 4; mi++)
        #pragma unroll
        for (int ni = 0; ni < 4; ni++) acc[mi][ni] = (f32x4){0.f, 0.f, 0.f, 0.f};

    const uint4* xb4 = (const uint4*)Xb + (size_t)R * 4096;
    uint4 areg[4];
    #pragma unroll
    for (int i = 0; i < 4; i++) areg[i] = xb4[i * 256 + t];   // K-step 0

    for (int S = 0; S < 4; S++) {
        uint4* adst = (uint4*)Alds;
        #pragma unroll
        for (int i = 0; i < 4; i++) adst[i * 256 + t] = areg[i];
        __syncthreads();
        if (S < 3) {
            #pragma unroll
            for (int i = 0; i < 4; i++) areg[i] = xb4[(size_t)(S + 1) * 1024 + i * 256 + t];
        }
        #pragma unroll
        for (int kf = 0; kf < 2; kf++) {
            bf16x8 a[4], b[4];
            #pragma unroll
            for (int mi = 0; mi < 4; mi++)
                a[mi] = *(const bf16x8*)(Alds + (wm * 4 + mi) * 1024 + kf * 512 + lane * 8);
            #pragma unroll
            for (int ni = 0; ni < 4; ni++)
                b[ni] = *(const bf16x8*)(Blds + (wn * 4 + ni) * 4096 + S * 1024 + kf * 512 + lane * 8);
            #pragma unroll
            for (int mi = 0; mi < 4; mi++)
                #pragma unroll
                for (int ni = 0; ni < 4; ni++)
                    acc[mi][ni] = __builtin_amdgcn_mfma_f32_16x16x32_bf16(a[mi], b[ni], acc[mi][ni], 0, 0, 0);
        }
        __syncthreads();
    }

    // epilogue: scale by out_norm[row], convert, store (C/D: col=lane&15, row=(lane>>4)*4+reg)
    const float* nrm = out_norm + (size_t)rr * N;
    u16* hr = h + (size_t)rr * N * OUT_F;
    #pragma unroll
    for (int mi = 0; mi < 4; mi++) {
        #pragma unroll
        for (int rg = 0; rg < 4; rg++) {
            int row = row0 + wm * 64 + mi * 16 + (lane >> 4) * 4 + rg;
            if (row >= N) continue;
            float nv = nrm[row];
            #pragma unroll
            for (int ni = 0; ni < 4; ni++) {
                int col = wn * 64 + ni * 16 + (lane & 15);
                hr[(size_t)row * OUT_F + col] = f32_to_bf16(acc[mi][ni][rg] * nv);
            }
        }
    }
}

// ---------- aggregate: 4 dst nodes per wave (16 lanes each), dwordx4 row gathers ----------
__global__ __launch_bounds__(256) void aggregate_kernel(const u16* __restrict__ sorted,
                                                        const u32* __restrict__ offs,
                                                        const u16* __restrict__ h,
                                                        float* __restrict__ Z,
                                                        int N, int nrel, int accflag) {
    int wid = (blockIdx.x * 256 + threadIdx.x) >> 6;
    int lane = threadIdx.x & 63;
    int g = lane >> 4, l16 = lane & 15;
    int dst = wid * 4 + g;
    int dstc = (dst < N) ? dst : (N - 1);
    float t[8] = {0.f, 0.f, 0.f, 0.f, 0.f, 0.f, 0.f, 0.f};
    for (int rr = 0; rr < nrel; rr++) {
        u32 b = offs[(size_t)rr * N + dstc];
        u32 e = offs[(size_t)rr * N + dstc + 1];
        u32 cnt = (dst < N) ? (e - b) : 0u;
        const uint4* hr = (const uint4*)(h + (size_t)rr * N * OUT_F);   // 16 uint4 per row
        float a[8] = {0.f, 0.f, 0.f, 0.f, 0.f, 0.f, 0.f, 0.f};
        u32 j = 0;
        for (; j + 8 <= cnt; j += 8) {
            u32 ids[8];
            #pragma unroll
            for (int q = 0; q < 8; q++) ids[q] = (u32)sorted[b + j + q];   // 16-lane broadcast
            uint4 rv[8];
            #pragma unroll
            for (int q = 0; q < 8; q++) rv[q] = hr[(size_t)ids[q] * 16 + l16];  // 32 rows in flight/wave
            #pragma unroll
            for (int q = 0; q < 8; q++) {
                a[0] += bf16lo(rv[q].x); a[1] += bf16hi(rv[q].x);
                a[2] += bf16lo(rv[q].y); a[3] += bf16hi(rv[q].y);
                a[4] += bf16lo(rv[q].z); a[5] += bf16hi(rv[q].z);
                a[6] += bf16lo(rv[q].w); a[7] += bf16hi(rv[q].w);
            }
        }
        for (; j < cnt; j++) {
            uint4 rv = hr[(size_t)sorted[b + j] * 16 + l16];
            a[0] += bf16lo(rv.x); a[1] += bf16hi(rv.x);
            a[2] += bf16lo(rv.y); a[3] += bf16hi(rv.y);
            a[4] += bf16lo(rv.z); a[5] += bf16hi(rv.z);
            a[6] += bf16lo(rv.w); a[7] += bf16hi(rv.w);
        }
        float inr = rsqrtf((float)max(cnt, 1u));
        #pragma unroll
        for (int k = 0; k < 8; k++) t[k] += inr * a[k];
    }
    if (dst < N) {
        float4* zp = (float4*)(Z + (size_t)dst * OUT_F + l16 * 8);
        if (accflag) {
            float4 z0 = zp[0], z1 = zp[1];
            z0.x += t[0]; z0.y += t[1]; z0.z += t[2]; z0.w += t[3];
            z1.x += t[4]; z1.y += t[5]; z1.z += t[6]; z1.w += t[7];
            zp[0] = z0; zp[1] = z1;
        } else {
            zp[0] = make_float4(t[0], t[1], t[2], t[3]);
            zp[1] = make_float4(t[4], t[5], t[6], t[7]);
        }
    }
}

// ---------- host ----------
extern "C" void kernel_launch(void* const* d_in, const int* in_sizes, int n_in,
                              void* d_out, int out_size, void* d_ws, size_t ws_size,
                              hipStream_t stream) {
    const float* X = (const float*)d_in[0];
    const float* W = (const float*)d_in[1];
    const int* EI = (const int*)d_in[2];
    float* Z = (float*)d_out;
    const int N = in_sizes[0] / IN_F;
    const int E = in_sizes[2] / (NUM_REL * 2);
    const int NB = (N + BN - 1) / BN;
    const int RBcnt = (N + 127) / 128;

    // persistent: sorted, offs, out_norm, bbd, bbs, xb, bimg, h
    // transient (overlaid on h region, all consumed before gemm writes h): ghd, ghs, bintot, part_dst, part_src
    size_t sorted_o, offs_o, out_norm_o, bbd_o, bbs_o, xb_o, bimg_o, h_o,
           ghd_o, ghs_o, bintot_o, part_dst_o, part_src_o;
    auto layout = [&](int nb) -> size_t {
        size_t cur = 0;
        auto alloc = [&](size_t bytes) {
            size_t o = cur; cur = (cur + bytes + 255) & ~(size_t)255; return o;
        };
        int BINS = nb * NB;
        size_t TE = (size_t)nb * E;
        sorted_o   = alloc(TE * 2);
        offs_o     = alloc(((size_t)nb * N + 1) * 4);
        out_norm_o = alloc((size_t)nb * N * 4);
        bbd_o      = alloc((size_t)(BINS + 1) * 4);
        bbs_o      = alloc((size_t)(BINS + 1) * 4);
        xb_o       = alloc((size_t)RBcnt * 4096 * 16);
        bimg_o     = alloc((size_t)NUM_REL * 4096 * 16);
        h_o        = alloc((size_t)nb * N * OUT_F * 2);
        size_t hend = cur;
        size_t ov = h_o;
        auto oalloc = [&](size_t bytes) {
            size_t o = ov; ov = (ov + bytes + 255) & ~(size_t)255; return o;
        };
        ghd_o      = oalloc((size_t)BINS * PBX * 4);
        ghs_o      = oalloc((size_t)BINS * PBX * 4);
        bintot_o   = oalloc((size_t)2 * BINS * 4);
        part_dst_o = oalloc(TE * 4);
        part_src_o = oalloc(TE);
        return (ov > hend) ? ov : hend;
    };
    int nb = NUM_REL;
    while (nb > 1 && layout(nb) > ws_size) nb >>= 1;
    layout(nb);
    char* ws = (char*)d_ws;
    const int nbatches = (NUM_REL + nb - 1) / nb;

    u16* xb = (u16*)(ws + xb_o);
    u16* bimg = (u16*)(ws + bimg_o);

    // one-time fragment-image prep (independent of the partition pipeline)
    int nchunks = RBcnt * 4096;
    xb_kernel<<<(nchunks + 255) / 256, 256, 0, stream>>>(X, xb, N, nchunks);
    wt_kernel<<<(NUM_REL * 4096 + 255) / 256, 256, 0, stream>>>(W, bimg, NUM_REL);

    if (nbatches > 1)
        hipMemsetAsync(d_out, 0, (size_t)N * OUT_F * sizeof(float), stream);

    for (int r0 = 0; r0 < NUM_REL; r0 += nb) {
        int cur = min(nb, NUM_REL - r0);
        int BINS = cur * NB;
        u16* sorted   = (u16*)(ws + sorted_o);
        u32* offs     = (u32*)(ws + offs_o);
        float* out_norm = (float*)(ws + out_norm_o);
        u32* bbd      = (u32*)(ws + bbd_o);
        u32* bbs      = (u32*)(ws + bbs_o);
        u16* h        = (u16*)(ws + h_o);
        u32* ghd      = (u32*)(ws + ghd_o);
        u32* ghs      = (u32*)(ws + ghs_o);
        u32* bintot   = (u32*)(ws + bintot_o);
        u32* part_dst = (u32*)(ws + part_dst_o);
        u8* part_src  = (u8*)(ws + part_src_o);

        p1_hist<<<dim3(PBX, cur), PT, 2 * NB * 4, stream>>>(EI, ghd, ghs, E, NB, r0);
        p2a_scan<<<(2 * BINS + 3) / 4, 256, 0, stream>>>(ghd, ghs, bintot, BINS);
        p2b_scan<<<1, 1024, 0, stream>>>(bintot, bbd, bbs, BINS);
        p3_scatter<<<dim3(PBX, cur), PT, 4 * NB * 4, stream>>>(
            EI, ghd, ghs, bbd, bbs, part_dst, part_src, E, NB, r0);
        srccount_kernel<<<dim3(NB, cur), 256, 0, stream>>>(part_src, bbs, out_norm, N, NB);
        p4_sort<<<dim3(NB, cur), 256, 0, stream>>>(part_dst, bbd, offs, sorted, N, NB, cur);
        gemm_kernel<<<dim3(RBcnt, cur), 256, 0, stream>>>(xb, bimg, out_norm, h, N, r0);
        aggregate_kernel<<<(N + 15) / 16, 256, 0, stream>>>(
            sorted, offs, h, Z, N, cur, (nbatches > 1) ? 1 : 0);
    }
}